// Round 13
// baseline (195.016 us; speedup 1.0000x reference)
//
#include <hip/hip_runtime.h>

#define DIM 128
#define EPS 1e-5f

typedef short           bf16x8 __attribute__((ext_vector_type(8)));
typedef unsigned short  u16x8  __attribute__((ext_vector_type(8)));
typedef float           f32x4  __attribute__((ext_vector_type(4)));

__device__ __forceinline__ unsigned short f2b(float f) {
    unsigned int u = __builtin_bit_cast(unsigned int, f);
    unsigned int r = (u + 0x7FFFu + ((u >> 16) & 1u)) >> 16;   // RNE
    return (unsigned short)r;
}
__device__ __forceinline__ bf16x8 ldw8(const float* __restrict__ p) {
    f32x4 a = *reinterpret_cast<const f32x4*>(p);
    f32x4 b = *reinterpret_cast<const f32x4*>(p + 4);
    bf16x8 r;
    #pragma unroll
    for (int j = 0; j < 4; ++j) {
        r[j]     = (short)f2b(a[j]);
        r[j + 4] = (short)f2b(b[j]);
    }
    return r;
}

// ---------------------------------------------------------------------------
// K0: segment boundaries. bounds[b] = first n with batch[n] >= b.
// ---------------------------------------------------------------------------
__global__ __launch_bounds__(256) void k_bounds(
    const int* __restrict__ batch, int* __restrict__ bounds, int n_nodes, int nb)
{
    const int idx = blockIdx.x * blockDim.x + threadIdx.x;
    if (idx > n_nodes) return;
    const int cur  = (idx < n_nodes) ? batch[idx] : nb;
    const int prev = (idx > 0) ? batch[idx - 1] : -1;
    for (int b = prev + 1; b <= cur; ++b) bounds[b] = idx;
}

// ---------------------------------------------------------------------------
// K1 (R5 fused, byte-optimal: h read from HBM exactly once) with two changes:
//   (a) phase-3 stores are NORMAL (A/B vs R5's nontemporal — NT suspected of
//       throttling the write pipe; every 7 TB/s datapoint uses normal stores)
//   (b) precomputed bounds instead of in-block binary search.
// Phase 1: 16 lanes/graph register pool. Phase 2: wave 0 MFMA MLP -> vtile.
// Phase 3: re-walk segment (L3-warm) and store h_out = h + vtile[g].
// ---------------------------------------------------------------------------
__global__ __launch_bounds__(256) void k_fused(
    const float* __restrict__ h, const int* __restrict__ bounds,
    const float* __restrict__ vn,
    const float* __restrict__ W1, const float* __restrict__ b1,
    const float* __restrict__ lng, const float* __restrict__ lnb,
    const float* __restrict__ W2, const float* __restrict__ b2v,
    float* __restrict__ vn_out, float* __restrict__ h_out, int n_nodes)
{
    __shared__ int sb[17];
    __shared__ unsigned short xtile[16][136];   // bf16 MLP input tile (padded)
    __shared__ float vtile[16][132];            // f32 MLP output tile (padded)

    const int tid = threadIdx.x;
    const int G0  = blockIdx.x * 16;

    if (tid < 17) sb[tid] = bounds[G0 + tid];
    __syncthreads();

    const int gi = tid >> 4;    // graph within tile (0..15)
    const int j  = tid & 15;    // 8-feature slot: features j*8 .. j*8+7
    const int s = sb[gi], e = sb[gi + 1];

    // ---- phase 1: register-accumulated segment pool ----
    f32x4 a0 = (f32x4){0.f, 0.f, 0.f, 0.f};
    f32x4 a1 = (f32x4){0.f, 0.f, 0.f, 0.f};
    for (int n = s; n < e; ++n) {
        const float* p = h + (size_t)n * DIM + j * 8;
        a0 += *reinterpret_cast<const f32x4*>(p);
        a1 += *reinterpret_cast<const f32x4*>(p + 4);
    }
    const int cnt = e - s;
    const float inv = 1.0f / (float)(cnt > 1 ? cnt : 1);
    const float* vp = vn + (size_t)(G0 + gi) * DIM + j * 8;
    f32x4 v0 = *reinterpret_cast<const f32x4*>(vp);
    f32x4 v1 = *reinterpret_cast<const f32x4*>(vp + 4);
    u16x8 xv;
    #pragma unroll
    for (int q = 0; q < 4; ++q) {
        xv[q]     = f2b(fmaf(a0[q], inv, v0[q]));
        xv[q + 4] = f2b(fmaf(a1[q], inv, v1[q]));
    }
    *reinterpret_cast<u16x8*>(&xtile[gi][j * 8]) = xv;
    __syncthreads();

    // ---- phase 2: wave 0 runs the 2-layer MFMA MLP ----
    // A/B share the element->k bijection -> k-permutation safe.
    // C/D (m89-verified): col n = lane&15, row m = (lane>>4)*4 + reg.
    if (tid < 64) {
        const int row16 = tid & 15;
        const int kgrp  = tid >> 4;

        bf16x8 afrag[4];
        #pragma unroll
        for (int kk = 0; kk < 4; ++kk)
            afrag[kk] = *reinterpret_cast<const bf16x8*>(&xtile[row16][kgrp * 8 + kk * 32]);

        f32x4 acc[8];
        #pragma unroll
        for (int t = 0; t < 8; ++t) acc[t] = (f32x4){0.f, 0.f, 0.f, 0.f};
        #pragma unroll
        for (int t = 0; t < 8; ++t) {
            const float* wp = W1 + (size_t)(t * 16 + row16) * DIM + kgrp * 8;
            #pragma unroll
            for (int kk = 0; kk < 4; ++kk) {
                bf16x8 bfrag = ldw8(wp + kk * 32);
                acc[t] = __builtin_amdgcn_mfma_f32_16x16x32_bf16(afrag[kk], bfrag, acc[t], 0, 0, 0);
            }
        }

        float b1f[8], gf[8], bf_[8], b2f8[8];
        #pragma unroll
        for (int t = 0; t < 8; ++t) {
            const int f = t * 16 + row16;
            b1f[t]  = b1[f];
            gf[t]   = lng[f];
            bf_[t]  = lnb[f];
            b2f8[t] = b2v[f];
        }
        #pragma unroll
        for (int t = 0; t < 8; ++t)
            #pragma unroll
            for (int r = 0; r < 4; ++r) acc[t][r] += b1f[t];

        // LayerNorm + ReLU -> z (bf16) back into xtile
        #pragma unroll
        for (int r = 0; r < 4; ++r) {
            float sm = 0.f, ss = 0.f;
            #pragma unroll
            for (int t = 0; t < 8; ++t) { sm += acc[t][r]; ss += acc[t][r] * acc[t][r]; }
            #pragma unroll
            for (int m = 1; m <= 8; m <<= 1) {
                sm += __shfl_xor(sm, m);
                ss += __shfl_xor(ss, m);
            }
            const float mu  = sm * (1.0f / 128.0f);
            const float var = ss * (1.0f / 128.0f) - mu * mu;
            const float rs  = rsqrtf(var + EPS);
            const int   gm  = kgrp * 4 + r;
            #pragma unroll
            for (int t = 0; t < 8; ++t) {
                float z = (acc[t][r] - mu) * rs * gf[t] + bf_[t];
                z = fmaxf(z, 0.f);
                xtile[gm][t * 16 + row16] = f2b(z);
            }
        }
        // wave-internal LDS ordering: reads below see this wave's writes

        bf16x8 afrag2[4];
        #pragma unroll
        for (int kk = 0; kk < 4; ++kk)
            afrag2[kk] = *reinterpret_cast<const bf16x8*>(&xtile[row16][kgrp * 8 + kk * 32]);

        f32x4 acc2[8];
        #pragma unroll
        for (int t = 0; t < 8; ++t) acc2[t] = (f32x4){0.f, 0.f, 0.f, 0.f};
        #pragma unroll
        for (int t = 0; t < 8; ++t) {
            const float* wp = W2 + (size_t)(t * 16 + row16) * DIM + kgrp * 8;
            #pragma unroll
            for (int kk = 0; kk < 4; ++kk) {
                bf16x8 bfrag = ldw8(wp + kk * 32);
                acc2[t] = __builtin_amdgcn_mfma_f32_16x16x32_bf16(afrag2[kk], bfrag, acc2[t], 0, 0, 0);
            }
        }

        // result -> LDS vtile (2-way bank aliasing only; free per m136)
        #pragma unroll
        for (int r = 0; r < 4; ++r) {
            const int gm = kgrp * 4 + r;
            #pragma unroll
            for (int t = 0; t < 8; ++t)
                vtile[gm][t * 16 + row16] = acc2[t][r] + b2f8[t];
        }
    }
    __syncthreads();

    // ---- coalesced global vn_out store from vtile ----
    {
        const float* src = &vtile[gi][j * 8];
        float* dst = vn_out + (size_t)(G0 + gi) * DIM + j * 8;
        *reinterpret_cast<f32x4*>(dst)     = *reinterpret_cast<const f32x4*>(src);
        *reinterpret_cast<f32x4*>(dst + 4) = *reinterpret_cast<const f32x4*>(src + 4);
    }

    // ---- phase 3: h_out = h + vtile[g]; NORMAL stores (the A/B variable) ----
    f32x4 w0 = *reinterpret_cast<const f32x4*>(&vtile[gi][j * 8]);
    f32x4 w1 = *reinterpret_cast<const f32x4*>(&vtile[gi][j * 8 + 4]);
    for (int n = s; n < e; ++n) {
        const float* p = h + (size_t)n * DIM + j * 8;
        f32x4 h0 = *reinterpret_cast<const f32x4*>(p);
        f32x4 h1 = *reinterpret_cast<const f32x4*>(p + 4);
        float* op = h_out + (size_t)n * DIM + j * 8;
        *reinterpret_cast<f32x4*>(op)     = h0 + w0;
        *reinterpret_cast<f32x4*>(op + 4) = h1 + w1;
    }
}

// ---------------------------------------------------------------------------
extern "C" void kernel_launch(void* const* d_in, const int* in_sizes, int n_in,
                              void* d_out, int out_size, void* d_ws, size_t ws_size,
                              hipStream_t stream)
{
    const float* h    = (const float*)d_in[0];
    const int*   bat  = (const int*)d_in[1];
    const float* vn   = (const float*)d_in[2];
    const float* W1   = (const float*)d_in[3];
    const float* b1   = (const float*)d_in[4];
    const float* lng  = (const float*)d_in[5];
    const float* lnb  = (const float*)d_in[6];
    const float* W2   = (const float*)d_in[7];
    const float* b2v  = (const float*)d_in[8];

    const int n_nodes = in_sizes[0] / DIM;   // 500000
    const int nb      = in_sizes[2] / DIM;   // 8192

    float* out    = (float*)d_out;           // f32 output buffer
    float* h_out  = out;
    float* vn_out = out + (size_t)n_nodes * DIM;
    int*   bounds = (int*)d_ws;              // (nb+1) ints

    k_bounds<<<(n_nodes + 256) / 256, 256, 0, stream>>>(bat, bounds, n_nodes, nb);
    k_fused<<<nb / 16, 256, 0, stream>>>(h, bounds, vn, W1, b1, lng, lnb,
                                         W2, b2v, vn_out, h_out, n_nodes);
}